// Round 6
// baseline (1125.191 us; speedup 1.0000x reference)
//
#include <hip/hip_runtime.h>
#include <stdint.h>

#define DIMC   1024
#define HEADS  16
#define HD     64
#define HIDDEN 4096
#define BATCH  4
#define SEQ    2048
#define ROWS   (BATCH*SEQ)   // 8192

typedef unsigned short u16;
typedef __attribute__((ext_vector_type(8))) short bf16x8;
typedef __attribute__((ext_vector_type(4))) float f32x4;
typedef __attribute__((address_space(1))) void* gas_ptr;
typedef __attribute__((address_space(3))) void* las_ptr;

struct u16x4s { u16 x, y, z, w; };

__device__ __forceinline__ u16 f2bf(float f) {
    union { float f; uint32_t u; } x; x.f = f;
    uint32_t r = (x.u + 0x7FFFu + ((x.u >> 16) & 1u)) >> 16;
    return (u16)r;
}
__device__ __forceinline__ u16 f2bf_rtz(float f) {   // cheap truncation; bias cancels in P/l ratio
    union { float f; uint32_t u; } x; x.f = f;
    return (u16)(x.u >> 16);
}

__device__ __forceinline__ bf16x8 ld_frag(const u16* p) {
    return *(const bf16x8*)p;
}

// ---------------- weight transpose: w[K][N] f32 -> wt[N][K] bf16 ----------------
__global__ __launch_bounds__(256) void transpose_bf16(const float* __restrict__ w,
                                                      u16* __restrict__ wt, int K, int N) {
    __shared__ float tile[32][33];
    int bx = blockIdx.x * 32, by = blockIdx.y * 32;
    int tx = threadIdx.x & 31, ty = threadIdx.x >> 5;   // 32 x 8
#pragma unroll
    for (int i = 0; i < 32; i += 8)
        tile[ty + i][tx] = w[(size_t)(by + ty + i) * N + bx + tx];
    __syncthreads();
#pragma unroll
    for (int i = 0; i < 32; i += 8)
        wt[(size_t)(bx + ty + i) * K + by + tx] = f2bf(tile[tx][ty + i]);
}

// ---------------- V transpose: vb[BH][N][64] bf16 -> vt[BH][64][N] bf16 ----------------
__global__ __launch_bounds__(256) void transpose_v(const u16* __restrict__ vb,
                                                   u16* __restrict__ vt) {
    __shared__ u16 t[64][72];
    const int bh = blockIdx.y;
    const int n0 = blockIdx.x * 64;
    const int tid = threadIdx.x;
    const int r = tid >> 3, c = (tid & 7) * 8;   // r: 0..31, c: 0..56 step 8
    const u16* src = vb + ((size_t)bh * SEQ + n0) * HD;
#pragma unroll
    for (int half = 0; half < 2; half++) {
        int n = half * 32 + r;
        *(bf16x8*)&t[n][c] = *(const bf16x8*)(src + (size_t)n * HD + c);
    }
    __syncthreads();
    u16* dst = vt + (size_t)bh * HD * SEQ + n0;
#pragma unroll
    for (int half = 0; half < 2; half++) {
        int d = half * 32 + r;
        u16 tmp[8];
#pragma unroll
        for (int j = 0; j < 8; j++) tmp[j] = t[c + j][d];
        *(bf16x8*)(dst + (size_t)d * SEQ + c) = *(const bf16x8*)tmp;
    }
}

// ---------------- layernorm: f32 row -> bf16 row ----------------
__global__ __launch_bounds__(256) void ln_fwd(const float* __restrict__ x,
                                              const float* __restrict__ g,
                                              const float* __restrict__ bta,
                                              u16* __restrict__ out) {
    __shared__ float red[8];
    int row = blockIdx.x, tid = threadIdx.x;
    int wave = tid >> 6, lane = tid & 63;
    const float4 v = ((const float4*)(x + (size_t)row * DIMC))[tid];
    float s  = v.x + v.y + v.z + v.w;
    float s2 = v.x * v.x + v.y * v.y + v.z * v.z + v.w * v.w;
#pragma unroll
    for (int off = 1; off < 64; off <<= 1) {
        s  += __shfl_xor(s,  off, 64);
        s2 += __shfl_xor(s2, off, 64);
    }
    if (lane == 0) { red[wave] = s; red[4 + wave] = s2; }
    __syncthreads();
    s  = red[0] + red[1] + red[2] + red[3];
    s2 = red[4] + red[5] + red[6] + red[7];
    float mu = s * (1.f / DIMC);
    float rs = rsqrtf(s2 * (1.f / DIMC) - mu * mu + 1e-5f);
    float4 gv = ((const float4*)g)[tid];
    float4 bv = ((const float4*)bta)[tid];
    u16x4s o;
    o.x = f2bf((v.x - mu) * rs * gv.x + bv.x);
    o.y = f2bf((v.y - mu) * rs * gv.y + bv.y);
    o.z = f2bf((v.z - mu) * rs * gv.z + bv.z);
    o.w = f2bf((v.w - mu) * rs * gv.w + bv.w);
    *(u16x4s*)(out + (size_t)row * DIMC + tid * 4) = o;
}

// ---------------- GEMM v2: C[M][N] = A[M][K](bf16) * Bt[N][K](bf16)^T + bias ----------------
// BK=64, A double-buffered in LDS (2 bufs x 2 k-planes x 128x32, zero-conflict XOR swizzle
// per plane, verified R5). B fragments load DIRECTLY global->VGPR (L2-resident weights),
// ping-pong register sets prefetched one iter ahead. One barrier per BK=64; next-tile
// global_load_lds + next B loads issue a full compute-phase before the barrier that drains
// them -> exposed latency ~0, and LDS pipe traffic halves (no B staging/reads).
#define EPI_F32_RESID 0
#define EPI_BF16      1
#define EPI_BF16_GELU 2
#define EPI_QKV       3

__global__ __launch_bounds__(256) void gemm_bt(
    const u16* __restrict__ A, const u16* __restrict__ Bt,
    const float* __restrict__ bias, const float* __restrict__ resid,
    float* __restrict__ outf, u16* __restrict__ outb,
    int M, int N, int K, int epi,
    u16* __restrict__ qb, u16* __restrict__ kbuf, u16* __restrict__ vb) {
    __shared__ u16 As[2][2][128 * 32];   // [buf][kplane][...], 32 KB
    const int tid  = threadIdx.x;
    const int wave = tid >> 6, lane = tid & 63;
    const int quad = lane >> 4, l16 = lane & 15;
    const int bm0 = blockIdx.y * 128, bn0 = blockIdx.x * 128;
    const int wm = (wave >> 1) * 64, wn = (wave & 1) * 64;

    f32x4 acc[4][4];
#pragma unroll
    for (int i = 0; i < 4; i++)
#pragma unroll
        for (int j = 0; j < 4; j++) acc[i][j] = (f32x4){0.f, 0.f, 0.f, 0.f};

    // A staging: wave covers rows [wave*32, wave*32+32); per plane two 16-row issues.
    // lane -> row lane>>2, source chunk (lane&3)^((lane>>3)&3): lane-ordered LDS dest
    // realizes the swizzled layout (row offset 16 preserves the key).
    const int sr  = lane >> 2;
    const int scs = ((lane & 3) ^ ((lane >> 3) & 3)) * 8;
    const u16* gA = A + (size_t)(bm0 + wave * 32 + sr) * K + scs;
    const int sw = (l16 >> 1) & 3;   // read-side swizzle key

    // B direct: lane covers Bt row (bn0+wn+t*16+l16), cols quad*8..+7 (exact MFMA B layout)
    const u16* pB = Bt + (size_t)(bn0 + wn + l16) * K + quad * 8;

    auto stageA = [&](int buf, int k0) {
#pragma unroll
        for (int p = 0; p < 2; p++) {
            u16* s = (u16*)As[buf][p] + wave * 1024;
            const u16* g = gA + k0 + p * 32;
            __builtin_amdgcn_global_load_lds((gas_ptr)(g),                    (las_ptr)(s),       16, 0, 0);
            __builtin_amdgcn_global_load_lds((gas_ptr)(g + 16 * (size_t)K),   (las_ptr)(s + 512), 16, 0, 0);
        }
    };
    auto loadB = [&](bf16x8 (&dst)[8], int k0) {
#pragma unroll
        for (int ks = 0; ks < 2; ks++)
#pragma unroll
            for (int t = 0; t < 4; t++)
                dst[ks * 4 + t] = ld_frag(pB + (size_t)t * 16 * K + k0 + ks * 32);
    };

    bf16x8 b0[8], b1[8];
    stageA(0, 0);
    loadB(b0, 0);

    const int nt = K >> 6;   // K is 1024 or 4096 -> nt 16 or 64, always even
    auto body = [&](bf16x8 (&bc)[8], bf16x8 (&bn)[8], int t2, int buf) {
        __syncthreads();   // drains stageA(buf) + loadB(bc) issued one compute-phase ago
        bf16x8 af[2][4];
#pragma unroll
        for (int p = 0; p < 2; p++)
#pragma unroll
            for (int t = 0; t < 4; t++)
                af[p][t] = ld_frag((u16*)As[buf][p] + (wm + t * 16 + l16) * 32 + (quad ^ sw) * 8);
        if (t2 + 1 < nt) stageA(buf ^ 1, (t2 + 1) << 6);
#pragma unroll
        for (int i = 0; i < 4; i++)
#pragma unroll
            for (int j = 0; j < 4; j++)
                acc[i][j] = __builtin_amdgcn_mfma_f32_16x16x32_bf16(af[0][i], bc[j], acc[i][j], 0, 0, 0);
        if (t2 + 1 < nt) loadB(bn, (t2 + 1) << 6);
#pragma unroll
        for (int i = 0; i < 4; i++)
#pragma unroll
            for (int j = 0; j < 4; j++)
                acc[i][j] = __builtin_amdgcn_mfma_f32_16x16x32_bf16(af[1][i], bc[4 + j], acc[i][j], 0, 0, 0);
    };

    for (int t2 = 0; t2 < nt; t2 += 2) {
        body(b0, b1, t2,     0);
        body(b1, b0, t2 + 1, 1);
    }

    // epilogue: C[row=quad*4+r][col=l16] per 16x16 tile
#pragma unroll
    for (int j = 0; j < 4; j++) {
        int gn = bn0 + wn + j * 16 + l16;
        float bv = bias[gn];
#pragma unroll
        for (int i = 0; i < 4; i++) {
            int gmb = bm0 + wm + i * 16 + quad * 4;
#pragma unroll
            for (int r = 0; r < 4; r++) {
                int gm = gmb + r;
                float v = acc[i][j][r] + bv;
                if (epi == EPI_F32_RESID) {
                    outf[(size_t)gm * N + gn] = resid[(size_t)gm * N + gn] + v;
                } else if (epi == EPI_BF16) {
                    outb[(size_t)gm * N + gn] = f2bf(v);
                } else if (epi == EPI_BF16_GELU) {
                    float gg = 0.5f * v * (1.f + erff(v * 0.70710678118654752f));
                    outb[(size_t)gm * N + gn] = f2bf(gg);
                } else {  // QKV scatter: all three contiguous [BH][N][64]
                    int which = gn >> 10, hd_ = gn & 1023;
                    int h = hd_ >> 6, d = hd_ & 63;
                    int b = gm >> 11, n = gm & 2047;
                    u16* base = (which == 0) ? qb : (which == 1) ? kbuf : vb;
                    size_t bh = (size_t)(b * HEADS + h);
                    base[(bh * SEQ + n) * HD + d] = f2bf(v);
                }
            }
        }
    }
}

// ---------------- flash attention v2 ----------------
__global__ __launch_bounds__(256) void attn_fwd(const u16* __restrict__ q,
                                                const u16* __restrict__ kk,
                                                const u16* __restrict__ vt,
                                                u16* __restrict__ o) {
    __shared__ u16 Ks[64 * 64];      // [key][d], chunk-swizzled
    __shared__ u16 Vs[64 * 64];      // [d][key], chunk-swizzled
    __shared__ u16 Pb[4][32 * 72];   // per-wave P scratch, row stride 72 u16
    const int tid = threadIdx.x;
    const int wave = tid >> 6, lane = tid & 63;
    const int quad = lane >> 4, l16 = lane & 15;
    const int bh = blockIdx.y;
    const int b = bh >> 4, h = bh & 15;
    const int q0 = blockIdx.x * 128 + wave * 32;

    const u16* Q  = q  + (size_t)bh * SEQ * HD;
    const u16* Kp = kk + (size_t)bh * SEQ * HD;
    const u16* VT = vt + (size_t)bh * HD * SEQ;

    bf16x8 qf[2][2];
#pragma unroll
    for (int rb = 0; rb < 2; rb++)
#pragma unroll
        for (int hf = 0; hf < 2; hf++)
            qf[rb][hf] = ld_frag(Q + (size_t)(q0 + rb * 16 + l16) * HD + hf * 32 + quad * 8);

    f32x4 of[2][4], lsum[2];
#pragma unroll
    for (int rb = 0; rb < 2; rb++) {
        lsum[rb] = (f32x4){0.f, 0.f, 0.f, 0.f};
#pragma unroll
        for (int dc = 0; dc < 4; dc++) of[rb][dc] = (f32x4){0.f, 0.f, 0.f, 0.f};
    }

    const short one_bf = (short)0x3F80;
    const bf16x8 ones = {one_bf, one_bf, one_bf, one_bf, one_bf, one_bf, one_bf, one_bf};

    const int srow = lane >> 3;               // 0..7 within an 8-row issue
    const int schk = (lane & 7) ^ srow;       // XOR chunk swizzle applied at the source
    const u16* gK = Kp + (size_t)(wave * 16 + srow) * HD + schk * 8;
    const u16* gV = VT + (size_t)(wave * 16 + srow) * SEQ + schk * 8;
    u16* sK = Ks + (wave * 16) * 64;
    u16* sV = Vs + (wave * 16) * 64;
    u16* pb = Pb[wave];
    const int sw = l16 & 7;                   // read-side swizzle key

    for (int kb = 0; kb < SEQ; kb += 64) {
        __syncthreads();
        __builtin_amdgcn_global_load_lds((gas_ptr)(gK + (size_t)kb * HD),            (las_ptr)(sK),            16, 0, 0);
        __builtin_amdgcn_global_load_lds((gas_ptr)(gK + (size_t)(kb + 8) * HD),      (las_ptr)(sK + 8 * 64),   16, 0, 0);
        __builtin_amdgcn_global_load_lds((gas_ptr)(gV + kb),                         (las_ptr)(sV),            16, 0, 0);
        __builtin_amdgcn_global_load_lds((gas_ptr)(gV + kb + 8 * (size_t)SEQ),       (las_ptr)(sV + 8 * 64),   16, 0, 0);
        __syncthreads();

        // QK^T: s[rb][kblk], 16 MFMA off 8 kf reads
        f32x4 s[2][4];
#pragma unroll
        for (int kblk = 0; kblk < 4; kblk++) {
            const u16* krow = Ks + (kblk * 16 + l16) * 64;
            bf16x8 kf0 = ld_frag(krow + ((quad ^ sw) * 8));
            bf16x8 kf1 = ld_frag(krow + (((4 + quad) ^ sw) * 8));
            s[0][kblk] = __builtin_amdgcn_mfma_f32_16x16x32_bf16(qf[0][0], kf0, (f32x4){0.f,0.f,0.f,0.f}, 0, 0, 0);
            s[0][kblk] = __builtin_amdgcn_mfma_f32_16x16x32_bf16(qf[0][1], kf1, s[0][kblk], 0, 0, 0);
            s[1][kblk] = __builtin_amdgcn_mfma_f32_16x16x32_bf16(qf[1][0], kf0, (f32x4){0.f,0.f,0.f,0.f}, 0, 0, 0);
            s[1][kblk] = __builtin_amdgcn_mfma_f32_16x16x32_bf16(qf[1][1], kf1, s[1][kblk], 0, 0, 0);
        }

        // exp (fixed max) -> bf16 P in padded LDS
#pragma unroll
        for (int rb = 0; rb < 2; rb++)
#pragma unroll
            for (int kblk = 0; kblk < 4; kblk++)
#pragma unroll
                for (int r = 0; r < 4; r++) {
                    float p = __expf(s[rb][kblk][r] * 0.125f);
                    pb[(rb * 16 + quad * 4 + r) * 72 + kblk * 16 + l16] = f2bf_rtz(p);
                }

        // P -> A-layout frags
        bf16x8 pf[2][2];
#pragma unroll
        for (int rb = 0; rb < 2; rb++)
#pragma unroll
            for (int hf = 0; hf < 2; hf++)
                pf[rb][hf] = ld_frag(pb + (rb * 16 + l16) * 72 + hf * 32 + quad * 8);

        // PV + row-sum, 20 MFMA off 8 vf reads
#pragma unroll
        for (int hf = 0; hf < 2; hf++) {
#pragma unroll
            for (int dc = 0; dc < 4; dc++) {
                const u16* vrow = Vs + (dc * 16 + l16) * 64;
                bf16x8 vf = ld_frag(vrow + (((hf * 4 + quad) ^ sw) * 8));
                of[0][dc] = __builtin_amdgcn_mfma_f32_16x16x32_bf16(pf[0][hf], vf, of[0][dc], 0, 0, 0);
                of[1][dc] = __builtin_amdgcn_mfma_f32_16x16x32_bf16(pf[1][hf], vf, of[1][dc], 0, 0, 0);
            }
            lsum[0] = __builtin_amdgcn_mfma_f32_16x16x32_bf16(pf[0][hf], ones, lsum[0], 0, 0, 0);
            lsum[1] = __builtin_amdgcn_mfma_f32_16x16x32_bf16(pf[1][hf], ones, lsum[1], 0, 0, 0);
        }
    }

#pragma unroll
    for (int rb = 0; rb < 2; rb++) {
        float rl[4];
#pragma unroll
        for (int r = 0; r < 4; r++) rl[r] = 1.f / lsum[rb][r];
#pragma unroll
        for (int dc = 0; dc < 4; dc++)
#pragma unroll
            for (int r = 0; r < 4; r++) {
                float val = of[rb][dc][r] * rl[r];
                o[(size_t)(b * SEQ + q0 + rb * 16 + quad * 4 + r) * DIMC + h * HD + dc * 16 + l16] = f2bf(val);
            }
    }
}

// ---------------- launch ----------------
extern "C" void kernel_launch(void* const* d_in, const int* in_sizes, int n_in,
                              void* d_out, int out_size, void* d_ws, size_t ws_size,
                              hipStream_t stream) {
    (void)in_sizes; (void)n_in; (void)out_size; (void)ws_size;
    const float* x      = (const float*)d_in[0];
    const float* ln1_g  = (const float*)d_in[1];
    const float* ln1_b  = (const float*)d_in[2];
    const float* ln2_g  = (const float*)d_in[3];
    const float* ln2_b  = (const float*)d_in[4];
    const float* w_qkv  = (const float*)d_in[5];
    const float* b_qkv  = (const float*)d_in[6];
    const float* w_proj = (const float*)d_in[7];
    const float* b_proj = (const float*)d_in[8];
    const float* w_fc1  = (const float*)d_in[9];
    const float* b_fc1  = (const float*)d_in[10];
    const float* w_fc2  = (const float*)d_in[11];
    const float* b_fc2  = (const float*)d_in[12];

    char* ws = (char*)d_ws;
    u16*   wqkvT  = (u16*)(ws);                 // 3072x1024 bf16 = 6 MB
    u16*   wprojT = (u16*)(ws + 6291456);       // 1024x1024 = 2 MB
    u16*   wfc1T  = (u16*)(ws + 8388608);       // 4096x1024 = 8 MB
    u16*   wfc2T  = (u16*)(ws + 16777216);      // 1024x4096 = 8 MB
    u16*   hb     = (u16*)(ws + 25165824);      // 8192x1024 bf16 (LN1 out, reused as LN2 out)
    float* x1     = (float*)(ws + 41943040);    // 8192x1024 f32 (written by proj, read by fc2)
    u16*   vb     = (u16*)(ws + 41943040);      // 16 MB, aliases x1: dead before proj writes x1
    u16*   qb     = (u16*)(ws + 75497472);      // [B][H][N][64] bf16
    u16*   kb     = (u16*)(ws + 92274688);      // [B][H][N][64]
    u16*   vtb    = (u16*)(ws + 109051904);     // [B][H][64][N]
    u16*   ob     = (u16*)(ws + 125829120);     // 8192x1024 bf16 attn out
    u16*   a1     = qb;                         // 8192x4096 bf16, aliases q/k/vt/ob (dead by then)

    dim3 blk(256);
    transpose_bf16<<<dim3(3072 / 32, 1024 / 32), blk, 0, stream>>>(w_qkv,  wqkvT,  1024, 3072);
    transpose_bf16<<<dim3(1024 / 32, 1024 / 32), blk, 0, stream>>>(w_proj, wprojT, 1024, 1024);
    transpose_bf16<<<dim3(4096 / 32, 1024 / 32), blk, 0, stream>>>(w_fc1,  wfc1T,  1024, 4096);
    transpose_bf16<<<dim3(1024 / 32, 4096 / 32), blk, 0, stream>>>(w_fc2,  wfc2T,  4096, 1024);

    ln_fwd<<<dim3(ROWS), blk, 0, stream>>>(x, ln1_g, ln1_b, hb);

    gemm_bt<<<dim3(3072 / 128, ROWS / 128), blk, 0, stream>>>(
        hb, wqkvT, b_qkv, nullptr, nullptr, nullptr, ROWS, 3072, 1024, EPI_QKV, qb, kb, vb);

    transpose_v<<<dim3(SEQ / 64, BATCH * HEADS), blk, 0, stream>>>(vb, vtb);

    attn_fwd<<<dim3(SEQ / 128, BATCH * HEADS), blk, 0, stream>>>(qb, kb, vtb, ob);

    gemm_bt<<<dim3(1024 / 128, ROWS / 128), blk, 0, stream>>>(
        ob, wprojT, b_proj, x, x1, nullptr, ROWS, 1024, 1024, EPI_F32_RESID, nullptr, nullptr, nullptr);

    ln_fwd<<<dim3(ROWS), blk, 0, stream>>>(x1, ln2_g, ln2_b, hb);

    gemm_bt<<<dim3(4096 / 128, ROWS / 128), blk, 0, stream>>>(
        hb, wfc1T, b_fc1, nullptr, nullptr, a1, ROWS, 4096, 1024, EPI_BF16_GELU, nullptr, nullptr, nullptr);

    gemm_bt<<<dim3(1024 / 128, ROWS / 128), blk, 0, stream>>>(
        a1, wfc2T, b_fc2, x1, (float*)d_out, nullptr, ROWS, 1024, 4096, EPI_F32_RESID, nullptr, nullptr, nullptr);
}

// Round 7
// 634.439 us; speedup vs baseline: 1.7735x; 1.7735x over previous
//
#include <hip/hip_runtime.h>
#include <stdint.h>

#define DIMC   1024
#define HEADS  16
#define HD     64
#define HIDDEN 4096
#define BATCH  4
#define SEQ    2048
#define ROWS   (BATCH*SEQ)   // 8192

typedef unsigned short u16;
typedef __attribute__((ext_vector_type(8))) short bf16x8;
typedef __attribute__((ext_vector_type(4))) float f32x4;
typedef __attribute__((address_space(1))) void* gas_ptr;
typedef __attribute__((address_space(3))) void* las_ptr;

struct u16x4s { u16 x, y, z, w; };

__device__ __forceinline__ u16 f2bf(float f) {
    union { float f; uint32_t u; } x; x.f = f;
    uint32_t r = (x.u + 0x7FFFu + ((x.u >> 16) & 1u)) >> 16;
    return (u16)r;
}
__device__ __forceinline__ u16 f2bf_rtz(float f) {   // cheap truncation; bias cancels in P/l ratio
    union { float f; uint32_t u; } x; x.f = f;
    return (u16)(x.u >> 16);
}

__device__ __forceinline__ bf16x8 ld_frag(const u16* p) {
    return *(const bf16x8*)p;
}

// ---------------- weight transpose: w[K][N] f32 -> wt[N][K] bf16 ----------------
__global__ __launch_bounds__(256) void transpose_bf16(const float* __restrict__ w,
                                                      u16* __restrict__ wt, int K, int N) {
    __shared__ float tile[32][33];
    int bx = blockIdx.x * 32, by = blockIdx.y * 32;
    int tx = threadIdx.x & 31, ty = threadIdx.x >> 5;   // 32 x 8
#pragma unroll
    for (int i = 0; i < 32; i += 8)
        tile[ty + i][tx] = w[(size_t)(by + ty + i) * N + bx + tx];
    __syncthreads();
#pragma unroll
    for (int i = 0; i < 32; i += 8)
        wt[(size_t)(bx + ty + i) * K + by + tx] = f2bf(tile[tx][ty + i]);
}

// ---------------- V transpose: vb[BH][N][64] bf16 -> vt[BH][64][N] bf16 ----------------
__global__ __launch_bounds__(256) void transpose_v(const u16* __restrict__ vb,
                                                   u16* __restrict__ vt) {
    __shared__ u16 t[64][72];
    const int bh = blockIdx.y;
    const int n0 = blockIdx.x * 64;
    const int tid = threadIdx.x;
    const int r = tid >> 3, c = (tid & 7) * 8;   // r: 0..31, c: 0..56 step 8
    const u16* src = vb + ((size_t)bh * SEQ + n0) * HD;
#pragma unroll
    for (int half = 0; half < 2; half++) {
        int n = half * 32 + r;
        *(bf16x8*)&t[n][c] = *(const bf16x8*)(src + (size_t)n * HD + c);
    }
    __syncthreads();
    u16* dst = vt + (size_t)bh * HD * SEQ + n0;
#pragma unroll
    for (int half = 0; half < 2; half++) {
        int d = half * 32 + r;
        u16 tmp[8];
#pragma unroll
        for (int j = 0; j < 8; j++) tmp[j] = t[c + j][d];
        *(bf16x8*)(dst + (size_t)d * SEQ + c) = *(const bf16x8*)tmp;
    }
}

// ---------------- layernorm: f32 row -> bf16 row ----------------
__global__ __launch_bounds__(256) void ln_fwd(const float* __restrict__ x,
                                              const float* __restrict__ g,
                                              const float* __restrict__ bta,
                                              u16* __restrict__ out) {
    __shared__ float red[8];
    int row = blockIdx.x, tid = threadIdx.x;
    int wave = tid >> 6, lane = tid & 63;
    const float4 v = ((const float4*)(x + (size_t)row * DIMC))[tid];
    float s  = v.x + v.y + v.z + v.w;
    float s2 = v.x * v.x + v.y * v.y + v.z * v.z + v.w * v.w;
#pragma unroll
    for (int off = 1; off < 64; off <<= 1) {
        s  += __shfl_xor(s,  off, 64);
        s2 += __shfl_xor(s2, off, 64);
    }
    if (lane == 0) { red[wave] = s; red[4 + wave] = s2; }
    __syncthreads();
    s  = red[0] + red[1] + red[2] + red[3];
    s2 = red[4] + red[5] + red[6] + red[7];
    float mu = s * (1.f / DIMC);
    float rs = rsqrtf(s2 * (1.f / DIMC) - mu * mu + 1e-5f);
    float4 gv = ((const float4*)g)[tid];
    float4 bv = ((const float4*)bta)[tid];
    u16x4s o;
    o.x = f2bf((v.x - mu) * rs * gv.x + bv.x);
    o.y = f2bf((v.y - mu) * rs * gv.y + bv.y);
    o.z = f2bf((v.z - mu) * rs * gv.z + bv.z);
    o.w = f2bf((v.w - mu) * rs * gv.w + bv.w);
    *(u16x4s*)(out + (size_t)row * DIMC + tid * 4) = o;
}

// ---------------- GEMM (R5, proven): 128x128 tile, BK=32, zero-conflict swizzle ----------------
#define EPI_F32_RESID 0
#define EPI_BF16      1
#define EPI_BF16_GELU 2
#define EPI_QKV       3

__global__ __launch_bounds__(256) void gemm_bt(
    const u16* __restrict__ A, const u16* __restrict__ Bt,
    const float* __restrict__ bias, const float* __restrict__ resid,
    float* __restrict__ outf, u16* __restrict__ outb,
    int M, int N, int K, int epi,
    u16* __restrict__ qb, u16* __restrict__ kbuf, u16* __restrict__ vb) {
    __shared__ u16 As[128 * 32];   // 8 KB
    __shared__ u16 Bs[128 * 32];   // 8 KB
    const int tid  = threadIdx.x;
    const int wave = tid >> 6, lane = tid & 63;
    const int quad = lane >> 4, l16 = lane & 15;
    const int bm0 = blockIdx.y * 128, bn0 = blockIdx.x * 128;
    const int wm = (wave >> 1) * 64, wn = (wave & 1) * 64;

    f32x4 acc[4][4];
#pragma unroll
    for (int i = 0; i < 4; i++)
#pragma unroll
        for (int j = 0; j < 4; j++) acc[i][j] = (f32x4){0.f, 0.f, 0.f, 0.f};

    const int sr  = lane >> 2;
    const int scs = ((lane & 3) ^ ((lane >> 3) & 3)) * 8;
    const u16* gA = A  + (size_t)(bm0 + wave * 32 + sr) * K + scs;
    const u16* gB = Bt + (size_t)(bn0 + wave * 32 + sr) * K + scs;
    u16* sA0 = As + wave * 1024;
    u16* sB0 = Bs + wave * 1024;

    const int sw = (l16 >> 1) & 3;   // read-side swizzle key

    for (int k0 = 0; k0 < K; k0 += 32) {
        __syncthreads();
        __builtin_amdgcn_global_load_lds((gas_ptr)(gA + k0),                  (las_ptr)(sA0),       16, 0, 0);
        __builtin_amdgcn_global_load_lds((gas_ptr)(gA + k0 + 16 * (size_t)K), (las_ptr)(sA0 + 512), 16, 0, 0);
        __builtin_amdgcn_global_load_lds((gas_ptr)(gB + k0),                  (las_ptr)(sB0),       16, 0, 0);
        __builtin_amdgcn_global_load_lds((gas_ptr)(gB + k0 + 16 * (size_t)K), (las_ptr)(sB0 + 512), 16, 0, 0);
        __syncthreads();

        bf16x8 af[4], bfr[4];
#pragma unroll
        for (int t = 0; t < 4; t++) {
            af[t]  = ld_frag(As + (wm + t * 16 + l16) * 32 + (quad ^ sw) * 8);
            bfr[t] = ld_frag(Bs + (wn + t * 16 + l16) * 32 + (quad ^ sw) * 8);
        }
#pragma unroll
        for (int i = 0; i < 4; i++)
#pragma unroll
            for (int j = 0; j < 4; j++)
                acc[i][j] = __builtin_amdgcn_mfma_f32_16x16x32_bf16(af[i], bfr[j], acc[i][j], 0, 0, 0);
    }

#pragma unroll
    for (int j = 0; j < 4; j++) {
        int gn = bn0 + wn + j * 16 + l16;
        float bv = bias[gn];
#pragma unroll
        for (int i = 0; i < 4; i++) {
            int gmb = bm0 + wm + i * 16 + quad * 4;
#pragma unroll
            for (int r = 0; r < 4; r++) {
                int gm = gmb + r;
                float v = acc[i][j][r] + bv;
                if (epi == EPI_F32_RESID) {
                    outf[(size_t)gm * N + gn] = resid[(size_t)gm * N + gn] + v;
                } else if (epi == EPI_BF16) {
                    outb[(size_t)gm * N + gn] = f2bf(v);
                } else if (epi == EPI_BF16_GELU) {
                    float gg = 0.5f * v * (1.f + erff(v * 0.70710678118654752f));
                    outb[(size_t)gm * N + gn] = f2bf(gg);
                } else {  // QKV scatter: all three contiguous [BH][N][64]
                    int which = gn >> 10, hd_ = gn & 1023;
                    int h = hd_ >> 6, d = hd_ & 63;
                    int b = gm >> 11, n = gm & 2047;
                    u16* base = (which == 0) ? qb : (which == 1) ? kbuf : vb;
                    size_t bh = (size_t)(b * HEADS + h);
                    base[(bh * SEQ + n) * HD + d] = f2bf(v);
                }
            }
        }
    }
}

// ---------------- GEMM narrow-N: 128x64 tile, BK=32 ----------------
// For the N=1024 GEMMs (proj, fc2): 128x128 tiles give only 512 blocks = 2 blocks/CU,
// leaving the per-iter global_load_lds drain exposed (m114: implicit cross-block overlap
// is the latency hider). 128x64 doubles the grid to 4 blocks/CU. Waves 2(M)x2(N), wave
// tile 64x32, acc 4x2. Same zero-conflict XOR swizzle. 12 KB LDS, ~70 VGPR.
__global__ __launch_bounds__(256) void gemm_bt64(
    const u16* __restrict__ A, const u16* __restrict__ Bt,
    const float* __restrict__ bias, const float* __restrict__ resid,
    float* __restrict__ outf, int M, int N, int K) {
    __shared__ u16 As[128 * 32];   // 8 KB
    __shared__ u16 Bs[64 * 32];    // 4 KB
    const int tid  = threadIdx.x;
    const int wave = tid >> 6, lane = tid & 63;
    const int quad = lane >> 4, l16 = lane & 15;
    const int bm0 = blockIdx.y * 128, bn0 = blockIdx.x * 64;
    const int wm = (wave >> 1) * 64, wn = (wave & 1) * 32;

    f32x4 acc[4][2];
#pragma unroll
    for (int i = 0; i < 4; i++)
#pragma unroll
        for (int j = 0; j < 2; j++) acc[i][j] = (f32x4){0.f, 0.f, 0.f, 0.f};

    // A: wave stages rows [wave*32, wave*32+32) (two 16-row issues).
    // B: wave stages rows [wave*16, wave*16+16) (one issue). Same swizzle key per issue.
    const int sr  = lane >> 2;
    const int scs = ((lane & 3) ^ ((lane >> 3) & 3)) * 8;
    const u16* gA = A  + (size_t)(bm0 + wave * 32 + sr) * K + scs;
    const u16* gB = Bt + (size_t)(bn0 + wave * 16 + sr) * K + scs;
    u16* sA0 = As + wave * 1024;
    u16* sB0 = Bs + wave * 512;

    const int sw = (l16 >> 1) & 3;

    for (int k0 = 0; k0 < K; k0 += 32) {
        __syncthreads();
        __builtin_amdgcn_global_load_lds((gas_ptr)(gA + k0),                  (las_ptr)(sA0),       16, 0, 0);
        __builtin_amdgcn_global_load_lds((gas_ptr)(gA + k0 + 16 * (size_t)K), (las_ptr)(sA0 + 512), 16, 0, 0);
        __builtin_amdgcn_global_load_lds((gas_ptr)(gB + k0),                  (las_ptr)(sB0),       16, 0, 0);
        __syncthreads();

        bf16x8 af[4], bfr[2];
#pragma unroll
        for (int t = 0; t < 4; t++)
            af[t]  = ld_frag(As + (wm + t * 16 + l16) * 32 + (quad ^ sw) * 8);
#pragma unroll
        for (int t = 0; t < 2; t++)
            bfr[t] = ld_frag(Bs + (wn + t * 16 + l16) * 32 + (quad ^ sw) * 8);
#pragma unroll
        for (int i = 0; i < 4; i++)
#pragma unroll
            for (int j = 0; j < 2; j++)
                acc[i][j] = __builtin_amdgcn_mfma_f32_16x16x32_bf16(af[i], bfr[j], acc[i][j], 0, 0, 0);
    }

#pragma unroll
    for (int j = 0; j < 2; j++) {
        int gn = bn0 + wn + j * 16 + l16;
        float bv = bias[gn];
#pragma unroll
        for (int i = 0; i < 4; i++) {
            int gmb = bm0 + wm + i * 16 + quad * 4;
#pragma unroll
            for (int r = 0; r < 4; r++) {
                int gm = gmb + r;
                outf[(size_t)gm * N + gn] = resid[(size_t)gm * N + gn] + acc[i][j][r] + bv;
            }
        }
    }
}

// ---------------- flash attention v2 ----------------
__global__ __launch_bounds__(256) void attn_fwd(const u16* __restrict__ q,
                                                const u16* __restrict__ kk,
                                                const u16* __restrict__ vt,
                                                u16* __restrict__ o) {
    __shared__ u16 Ks[64 * 64];      // [key][d], chunk-swizzled
    __shared__ u16 Vs[64 * 64];      // [d][key], chunk-swizzled
    __shared__ u16 Pb[4][32 * 72];   // per-wave P scratch, row stride 72 u16
    const int tid = threadIdx.x;
    const int wave = tid >> 6, lane = tid & 63;
    const int quad = lane >> 4, l16 = lane & 15;
    const int bh = blockIdx.y;
    const int b = bh >> 4, h = bh & 15;
    const int q0 = blockIdx.x * 128 + wave * 32;

    const u16* Q  = q  + (size_t)bh * SEQ * HD;
    const u16* Kp = kk + (size_t)bh * SEQ * HD;
    const u16* VT = vt + (size_t)bh * HD * SEQ;

    bf16x8 qf[2][2];
#pragma unroll
    for (int rb = 0; rb < 2; rb++)
#pragma unroll
        for (int hf = 0; hf < 2; hf++)
            qf[rb][hf] = ld_frag(Q + (size_t)(q0 + rb * 16 + l16) * HD + hf * 32 + quad * 8);

    f32x4 of[2][4], lsum[2];
#pragma unroll
    for (int rb = 0; rb < 2; rb++) {
        lsum[rb] = (f32x4){0.f, 0.f, 0.f, 0.f};
#pragma unroll
        for (int dc = 0; dc < 4; dc++) of[rb][dc] = (f32x4){0.f, 0.f, 0.f, 0.f};
    }

    const short one_bf = (short)0x3F80;
    const bf16x8 ones = {one_bf, one_bf, one_bf, one_bf, one_bf, one_bf, one_bf, one_bf};

    const int srow = lane >> 3;               // 0..7 within an 8-row issue
    const int schk = (lane & 7) ^ srow;       // XOR chunk swizzle applied at the source
    const u16* gK = Kp + (size_t)(wave * 16 + srow) * HD + schk * 8;
    const u16* gV = VT + (size_t)(wave * 16 + srow) * SEQ + schk * 8;
    u16* sK = Ks + (wave * 16) * 64;
    u16* sV = Vs + (wave * 16) * 64;
    u16* pb = Pb[wave];
    const int sw = l16 & 7;                   // read-side swizzle key

    for (int kb = 0; kb < SEQ; kb += 64) {
        __syncthreads();
        __builtin_amdgcn_global_load_lds((gas_ptr)(gK + (size_t)kb * HD),            (las_ptr)(sK),            16, 0, 0);
        __builtin_amdgcn_global_load_lds((gas_ptr)(gK + (size_t)(kb + 8) * HD),      (las_ptr)(sK + 8 * 64),   16, 0, 0);
        __builtin_amdgcn_global_load_lds((gas_ptr)(gV + kb),                         (las_ptr)(sV),            16, 0, 0);
        __builtin_amdgcn_global_load_lds((gas_ptr)(gV + kb + 8 * (size_t)SEQ),       (las_ptr)(sV + 8 * 64),   16, 0, 0);
        __syncthreads();

        // QK^T: s[rb][kblk], 16 MFMA off 8 kf reads
        f32x4 s[2][4];
#pragma unroll
        for (int kblk = 0; kblk < 4; kblk++) {
            const u16* krow = Ks + (kblk * 16 + l16) * 64;
            bf16x8 kf0 = ld_frag(krow + ((quad ^ sw) * 8));
            bf16x8 kf1 = ld_frag(krow + (((4 + quad) ^ sw) * 8));
            s[0][kblk] = __builtin_amdgcn_mfma_f32_16x16x32_bf16(qf[0][0], kf0, (f32x4){0.f,0.f,0.f,0.f}, 0, 0, 0);
            s[0][kblk] = __builtin_amdgcn_mfma_f32_16x16x32_bf16(qf[0][1], kf1, s[0][kblk], 0, 0, 0);
            s[1][kblk] = __builtin_amdgcn_mfma_f32_16x16x32_bf16(qf[1][0], kf0, (f32x4){0.f,0.f,0.f,0.f}, 0, 0, 0);
            s[1][kblk] = __builtin_amdgcn_mfma_f32_16x16x32_bf16(qf[1][1], kf1, s[1][kblk], 0, 0, 0);
        }

        // exp (fixed max) -> bf16 P in padded LDS
#pragma unroll
        for (int rb = 0; rb < 2; rb++)
#pragma unroll
            for (int kblk = 0; kblk < 4; kblk++)
#pragma unroll
                for (int r = 0; r < 4; r++) {
                    float p = __expf(s[rb][kblk][r] * 0.125f);
                    pb[(rb * 16 + quad * 4 + r) * 72 + kblk * 16 + l16] = f2bf_rtz(p);
                }

        // P -> A-layout frags
        bf16x8 pf[2][2];
#pragma unroll
        for (int rb = 0; rb < 2; rb++)
#pragma unroll
            for (int hf = 0; hf < 2; hf++)
                pf[rb][hf] = ld_frag(pb + (rb * 16 + l16) * 72 + hf * 32 + quad * 8);

        // PV + row-sum, 20 MFMA off 8 vf reads
#pragma unroll
        for (int hf = 0; hf < 2; hf++) {
#pragma unroll
            for (int dc = 0; dc < 4; dc++) {
                const u16* vrow = Vs + (dc * 16 + l16) * 64;
                bf16x8 vf = ld_frag(vrow + (((hf * 4 + quad) ^ sw) * 8));
                of[0][dc] = __builtin_amdgcn_mfma_f32_16x16x32_bf16(pf[0][hf], vf, of[0][dc], 0, 0, 0);
                of[1][dc] = __builtin_amdgcn_mfma_f32_16x16x32_bf16(pf[1][hf], vf, of[1][dc], 0, 0, 0);
            }
            lsum[0] = __builtin_amdgcn_mfma_f32_16x16x32_bf16(pf[0][hf], ones, lsum[0], 0, 0, 0);
            lsum[1] = __builtin_amdgcn_mfma_f32_16x16x32_bf16(pf[1][hf], ones, lsum[1], 0, 0, 0);
        }
    }

#pragma unroll
    for (int rb = 0; rb < 2; rb++) {
        float rl[4];
#pragma unroll
        for (int r = 0; r < 4; r++) rl[r] = 1.f / lsum[rb][r];
#pragma unroll
        for (int dc = 0; dc < 4; dc++)
#pragma unroll
            for (int r = 0; r < 4; r++) {
                float val = of[rb][dc][r] * rl[r];
                o[(size_t)(b * SEQ + q0 + rb * 16 + quad * 4 + r) * DIMC + h * HD + dc * 16 + l16] = f2bf(val);
            }
    }
}

// ---------------- launch ----------------
extern "C" void kernel_launch(void* const* d_in, const int* in_sizes, int n_in,
                              void* d_out, int out_size, void* d_ws, size_t ws_size,
                              hipStream_t stream) {
    (void)in_sizes; (void)n_in; (void)out_size; (void)ws_size;
    const float* x      = (const float*)d_in[0];
    const float* ln1_g  = (const float*)d_in[1];
    const float* ln1_b  = (const float*)d_in[2];
    const float* ln2_g  = (const float*)d_in[3];
    const float* ln2_b  = (const float*)d_in[4];
    const float* w_qkv  = (const float*)d_in[5];
    const float* b_qkv  = (const float*)d_in[6];
    const float* w_proj = (const float*)d_in[7];
    const float* b_proj = (const float*)d_in[8];
    const float* w_fc1  = (const float*)d_in[9];
    const float* b_fc1  = (const float*)d_in[10];
    const float* w_fc2  = (const float*)d_in[11];
    const float* b_fc2  = (const float*)d_in[12];

    char* ws = (char*)d_ws;
    u16*   wqkvT  = (u16*)(ws);                 // 3072x1024 bf16 = 6 MB
    u16*   wprojT = (u16*)(ws + 6291456);       // 1024x1024 = 2 MB
    u16*   wfc1T  = (u16*)(ws + 8388608);       // 4096x1024 = 8 MB
    u16*   wfc2T  = (u16*)(ws + 16777216);      // 1024x4096 = 8 MB
    u16*   hb     = (u16*)(ws + 25165824);      // 8192x1024 bf16 (LN1 out, reused as LN2 out)
    float* x1     = (float*)(ws + 41943040);    // 8192x1024 f32 (written by proj, read by fc2)
    u16*   vb     = (u16*)(ws + 41943040);      // 16 MB, aliases x1: dead before proj writes x1
    u16*   qb     = (u16*)(ws + 75497472);      // [B][H][N][64] bf16
    u16*   kb     = (u16*)(ws + 92274688);      // [B][H][N][64]
    u16*   vtb    = (u16*)(ws + 109051904);     // [B][H][64][N]
    u16*   ob     = (u16*)(ws + 125829120);     // 8192x1024 bf16 attn out
    u16*   a1     = qb;                         // 8192x4096 bf16, aliases q/k/vt/ob (dead by then)

    dim3 blk(256);
    transpose_bf16<<<dim3(3072 / 32, 1024 / 32), blk, 0, stream>>>(w_qkv,  wqkvT,  1024, 3072);
    transpose_bf16<<<dim3(1024 / 32, 1024 / 32), blk, 0, stream>>>(w_proj, wprojT, 1024, 1024);
    transpose_bf16<<<dim3(4096 / 32, 1024 / 32), blk, 0, stream>>>(w_fc1,  wfc1T,  1024, 4096);
    transpose_bf16<<<dim3(1024 / 32, 4096 / 32), blk, 0, stream>>>(w_fc2,  wfc2T,  4096, 1024);

    ln_fwd<<<dim3(ROWS), blk, 0, stream>>>(x, ln1_g, ln1_b, hb);

    gemm_bt<<<dim3(3072 / 128, ROWS / 128), blk, 0, stream>>>(
        hb, wqkvT, b_qkv, nullptr, nullptr, nullptr, ROWS, 3072, 1024, EPI_QKV, qb, kb, vb);

    transpose_v<<<dim3(SEQ / 64, BATCH * HEADS), blk, 0, stream>>>(vb, vtb);

    attn_fwd<<<dim3(SEQ / 128, BATCH * HEADS), blk, 0, stream>>>(qb, kb, vtb, ob);

    gemm_bt64<<<dim3(1024 / 64, ROWS / 128), blk, 0, stream>>>(
        ob, wprojT, b_proj, x, x1, ROWS, 1024, 1024);

    ln_fwd<<<dim3(ROWS), blk, 0, stream>>>(x1, ln2_g, ln2_b, hb);

    gemm_bt<<<dim3(4096 / 128, ROWS / 128), blk, 0, stream>>>(
        hb, wfc1T, b_fc1, nullptr, nullptr, a1, ROWS, 4096, 1024, EPI_BF16_GELU, nullptr, nullptr, nullptr);

    gemm_bt64<<<dim3(1024 / 64, ROWS / 128), blk, 0, stream>>>(
        a1, wfc2T, b_fc2, x1, (float*)d_out, ROWS, 1024, 4096);
}